// Round 1
// baseline (238.735 us; speedup 1.0000x reference)
//
#include <hip/hip_runtime.h>
#include <hip/hip_bf16.h>
#include <stdint.h>

#define B_ 8
#define S_ 2048
#define F_ 512
#define E_ 512

typedef short bf16x8 __attribute__((ext_vector_type(8)));
typedef float f32x4 __attribute__((ext_vector_type(4)));

__device__ __forceinline__ f32x4 mfma16(bf16x8 a, bf16x8 b, f32x4 c) {
  return __builtin_amdgcn_mfma_f32_16x16x32_bf16(a, b, c, 0, 0, 0);
}

// async global->LDS, 16B per lane; dst is wave-uniform base, src per-lane
__device__ __forceinline__ void gll16(const void* g, void* l) {
  __builtin_amdgcn_global_load_lds(
      (const __attribute__((address_space(1))) void*)g,
      (__attribute__((address_space(3))) void*)l, 16, 0, 0);
}

// softmax scale folded into Q at projection time: log2(e)/sqrt(E)
constexpr float QSCALE = 0.0441941738f * 1.44269504f;

// ---------------- kernel 0: W[f][e] fp32 -> Wt[e][f] bf16 (x3) ----------------
__global__ void wtrans_kernel(const float* __restrict__ wq,
                              const float* __restrict__ wk,
                              const float* __restrict__ wv,
                              __hip_bfloat16* __restrict__ wt) {
  __shared__ float t[32][33];
  const float* w = (blockIdx.z == 0) ? wq : (blockIdx.z == 1 ? wk : wv);
  __hip_bfloat16* o = wt + (size_t)blockIdx.z * F_ * E_;
  int e0 = blockIdx.x * 32, f0 = blockIdx.y * 32;
  int tx = threadIdx.x, ty = threadIdx.y;
#pragma unroll
  for (int i = 0; i < 4; i++)
    t[ty + 8 * i][tx] = w[(size_t)(f0 + ty + 8 * i) * E_ + e0 + tx];
  __syncthreads();
#pragma unroll
  for (int i = 0; i < 4; i++)
    o[(size_t)(e0 + ty + 8 * i) * F_ + f0 + tx] = __float2bfloat16(t[tx][ty + 8 * i]);
}

// ---------------- kernel 1: QKV projection GEMM (bf16 MFMA) ----------------
// grid (128 m-tiles, 4 n-tiles, 3 {Q,K,V}); block 256 (4 waves, each 64x64)
__global__ __launch_bounds__(256, 2) void qkv_kernel(
    const float* __restrict__ x, const __hip_bfloat16* __restrict__ wt,
    __hip_bfloat16* __restrict__ Qb, __hip_bfloat16* __restrict__ Kb,
    __hip_bfloat16* __restrict__ Vt) {
  __shared__ __hip_bfloat16 Al[2][128][72];  // x-tile [m][k], pad 64->72
  __shared__ __hip_bfloat16 Bl[2][128][72];  // Wt-tile [n][k], pad

  int tid = threadIdx.x;
  int lane = tid & 63, w = tid >> 6;
  int el = lane & 15, g = lane >> 4;
  int m0 = blockIdx.x * 128, n0 = blockIdx.y * 128, z = blockIdx.z;
  const __hip_bfloat16* wz = wt + (size_t)z * F_ * E_;
  int wr = w >> 1, wc = w & 1;

  float4 fa[8];
  uint4 vb[4];

  auto load = [&](int kk) {
#pragma unroll
    for (int c = 0; c < 4; c++) {
      int id = tid + 256 * c;
      int row = id >> 3, k8 = (id & 7) * 8;
      const float* s = x + (size_t)(m0 + row) * F_ + kk * 64 + k8;
      fa[2 * c] = *(const float4*)s;
      fa[2 * c + 1] = *(const float4*)(s + 4);
      vb[c] = *(const uint4*)(wz + (size_t)(n0 + row) * F_ + kk * 64 + k8);
    }
  };
  auto store_lds = [&](int bf) {
#pragma unroll
    for (int c = 0; c < 4; c++) {
      int id = tid + 256 * c;
      int row = id >> 3, k8 = (id & 7) * 8;
      union { __hip_bfloat16 h[8]; uint4 u; } cv;
      cv.h[0] = __float2bfloat16(fa[2 * c].x);
      cv.h[1] = __float2bfloat16(fa[2 * c].y);
      cv.h[2] = __float2bfloat16(fa[2 * c].z);
      cv.h[3] = __float2bfloat16(fa[2 * c].w);
      cv.h[4] = __float2bfloat16(fa[2 * c + 1].x);
      cv.h[5] = __float2bfloat16(fa[2 * c + 1].y);
      cv.h[6] = __float2bfloat16(fa[2 * c + 1].z);
      cv.h[7] = __float2bfloat16(fa[2 * c + 1].w);
      *(uint4*)&Al[bf][row][k8] = cv.u;
      *(uint4*)&Bl[bf][row][k8] = vb[c];
    }
  };

  f32x4 acc[4][4] = {};
  load(0);
  store_lds(0);
  __syncthreads();

  for (int kk = 0; kk < 8; ++kk) {
    int bf = kk & 1;
    if (kk < 7) load(kk + 1);
#pragma unroll
    for (int ks = 0; ks < 2; ++ks) {
      bf16x8 av[4], bv[4];
#pragma unroll
      for (int mi = 0; mi < 4; mi++)
        av[mi] = *(const bf16x8*)((const char*)&Al[bf][0][0] +
                                  (wr * 64 + mi * 16 + el) * 144 + (ks * 32 + g * 8) * 2);
#pragma unroll
      for (int ni = 0; ni < 4; ni++)
        bv[ni] = *(const bf16x8*)((const char*)&Bl[bf][0][0] +
                                  (wc * 64 + ni * 16 + el) * 144 + (ks * 32 + g * 8) * 2);
#pragma unroll
      for (int mi = 0; mi < 4; mi++)
#pragma unroll
        for (int ni = 0; ni < 4; ni++)
          acc[mi][ni] = mfma16(av[mi], bv[ni], acc[mi][ni]);
    }
    if (kk < 7) store_lds(bf ^ 1);
    __syncthreads();
  }

  float sc = (z == 0) ? QSCALE : 1.0f;
#pragma unroll
  for (int mi = 0; mi < 4; mi++)
#pragma unroll
    for (int ni = 0; ni < 4; ni++)
#pragma unroll
      for (int r = 0; r < 4; r++) {
        int m = m0 + wr * 64 + mi * 16 + g * 4 + r;
        int n = n0 + wc * 64 + ni * 16 + el;
        __hip_bfloat16 v = __float2bfloat16(acc[mi][ni][r] * sc);
        if (z == 0) Qb[(size_t)m * E_ + n] = v;
        else if (z == 1) Kb[(size_t)m * E_ + n] = v;
        else {
          int b = m >> 11, sl = m & 2047;
          Vt[(size_t)b * E_ * S_ + (size_t)n * S_ + sl] = v;
        }
      }
}

// ---------------- kernel 2: flash attention ----------------
// grid 256: batch = bx&7 (XCD-affine), qt = bx>>3; block 256 = 4 waves x 16 q-rows
__global__ __launch_bounds__(256, 1) void attn_kernel(
    const __hip_bfloat16* __restrict__ Qb, const __hip_bfloat16* __restrict__ Kb,
    const __hip_bfloat16* __restrict__ Vt, float* __restrict__ out) {
  __shared__ __hip_bfloat16 Kl[2][32][512];   // [kv][e], chunk-XOR swizzled
  __shared__ __hip_bfloat16 Vl[2][512][32];   // [e][kv], chunk-XOR swizzled
  __shared__ __hip_bfloat16 Pl[4][16][40];    // per-wave P [q][kv], pad 32->40

  int tid = threadIdx.x;
  int lane = tid & 63, w = tid >> 6;
  int el = lane & 15, g = lane >> 4, x7 = lane & 7;
  int batch = blockIdx.x & 7, qt = blockIdx.x >> 3;
  int q0 = qt * 64 + w * 16;

  // Q fragments in registers (16 frags = whole K-dim of QK^T), pre-scaled in ws
  bf16x8 qf[16];
  {
    const __hip_bfloat16* qptr = Qb + (size_t)(batch * S_ + q0 + el) * E_ + g * 8;
#pragma unroll
    for (int s = 0; s < 16; s++) qf[s] = *(const bf16x8*)(qptr + 32 * s);
  }

  f32x4 o[32] = {};
  float m_run = -INFINITY, l_run = 0.f;

  const char* kbase_g = (const char*)(Kb + (size_t)batch * S_ * E_);
  const char* vbase_g = (const char*)(Vt + (size_t)batch * E_ * S_);
  // per-lane source offset for V staging: e = eb + (lane>>2); chunk c = (lane&3)^((lane>>3)&3)
  int vsrc_lane = (lane >> 2) * (S_ * 2) + 16 * ((lane & 3) ^ ((lane >> 3) & 3));

  auto stage = [&](int kt, int bf) {
#pragma unroll
    for (int i = 0; i < 8; i++) {  // K: one 1KB row per instr
      int kv = w * 8 + i;
      const char* src = kbase_g + ((size_t)(kt * 32 + kv) * E_ + 8 * (lane ^ i)) * 2;
      gll16(src, &Kl[bf][kv][0]);
    }
#pragma unroll
    for (int i = 0; i < 8; i++) {  // V: 16 e-rows (64B each) per instr
      int eb = (w * 8 + i) * 16;
      const char* src = vbase_g + (size_t)eb * (S_ * 2) + vsrc_lane + kt * 64;
      gll16(src, &Vl[bf][eb][0]);
    }
  };

  // K read bases: addr(f,s) = (16f+el)*1024 + (s>>1)*128 + ((4*(s&1)+g)^x7)*16
  int ka0 = el * 1024 + ((g ^ x7) << 4);
  int ka1 = el * 1024 + (((4 + g) ^ x7) << 4);
  // V read base: addr(ni) = ni*1024 + el*64 + ((g ^ ((el>>1)&3))<<4)
  int vbase_l = el * 64 + ((g ^ ((el >> 1) & 3)) << 4);

  auto compute = [&](int bf) {
    const char* kl = (const char*)&Kl[bf][0][0];
    const char* vl = (const char*)&Vl[bf][0][0];
    // swapped QK^T: st = K·Q  -> lane holds S^T[kv][q=el], kv = 16f + 4g + r
    f32x4 st[2] = {};
#pragma unroll
    for (int s = 0; s < 16; s++) {
      int base = ((s & 1) ? ka1 : ka0) + (s >> 1) * 128;
#pragma unroll
      for (int f = 0; f < 2; f++) {
        bf16x8 kf = *(const bf16x8*)(kl + base + f * 16384);
        st[f] = mfma16(kf, qf[s], st[f]);
      }
    }
    // online softmax (exp2 space; scale pre-folded into Q)
    float vmax = st[0][0];
#pragma unroll
    for (int r = 1; r < 4; r++) vmax = fmaxf(vmax, st[0][r]);
#pragma unroll
    for (int r = 0; r < 4; r++) vmax = fmaxf(vmax, st[1][r]);
    vmax = fmaxf(vmax, __shfl_xor(vmax, 16));
    vmax = fmaxf(vmax, __shfl_xor(vmax, 32));
    if (__any(vmax > m_run + 8.0f)) {  // defer-max rescale
      float m_new = fmaxf(m_run, vmax);
      float fac = exp2f(m_run - m_new);
      float fo[4];
#pragma unroll
      for (int r = 0; r < 4; r++) fo[r] = __shfl(fac, g * 4 + r);
#pragma unroll
      for (int ni = 0; ni < 32; ni++) {
        o[ni][0] *= fo[0]; o[ni][1] *= fo[1]; o[ni][2] *= fo[2]; o[ni][3] *= fo[3];
      }
      l_run *= fac;
      m_run = m_new;
    }
    float p[8];
    float rs = 0.f;
#pragma unroll
    for (int f = 0; f < 2; f++)
#pragma unroll
      for (int r = 0; r < 4; r++) {
        float e2 = exp2f(st[f][r] - m_run);
        p[4 * f + r] = e2;
        rs += e2;
      }
    rs += __shfl_xor(rs, 16);
    rs += __shfl_xor(rs, 32);
    l_run += rs;
    // P -> bf16 -> per-wave LDS [q][kv]
#pragma unroll
    for (int f = 0; f < 2; f++) {
      union { __hip_bfloat16 h[4]; uint2 u; } pk;
      pk.h[0] = __float2bfloat16(p[4 * f + 0]);
      pk.h[1] = __float2bfloat16(p[4 * f + 1]);
      pk.h[2] = __float2bfloat16(p[4 * f + 2]);
      pk.h[3] = __float2bfloat16(p[4 * f + 3]);
      *(uint2*)((char*)&Pl[w][0][0] + el * 80 + 32 * f + 8 * g) = pk.u;
    }
    asm volatile("s_waitcnt lgkmcnt(0)" ::: "memory");
    bf16x8 pa = *(const bf16x8*)((const char*)&Pl[w][0][0] + el * 80 + g * 16);
    // PV: O += P · V  (V read via transposed+swizzled LDS)
#pragma unroll
    for (int ni = 0; ni < 32; ni++) {
      bf16x8 vf = *(const bf16x8*)(vl + vbase_l + ni * 1024);
      o[ni] = mfma16(pa, vf, o[ni]);
    }
  };

  stage(0, 0);
  asm volatile("s_waitcnt vmcnt(0)" ::: "memory");
  __syncthreads();
  for (int kt = 0; kt < 64; ++kt) {
    int bf = kt & 1;
    if (kt < 63) stage(kt + 1, bf ^ 1);  // DMA overlaps compute
    compute(bf);
    asm volatile("s_waitcnt vmcnt(0)" ::: "memory");
    __syncthreads();
  }

  // epilogue: normalize by l and store fp32
  float linv[4];
#pragma unroll
  for (int r = 0; r < 4; r++) {
    float lr = __shfl(l_run, g * 4 + r);
    linv[r] = 1.0f / lr;
  }
  float* ob = out + (size_t)(batch * S_ + q0 + g * 4) * E_ + el;
#pragma unroll
  for (int ni = 0; ni < 32; ni++)
#pragma unroll
    for (int r = 0; r < 4; r++)
      ob[(size_t)r * E_ + ni * 16] = o[ni][r] * linv[r];
}

// ---------------- launch ----------------
extern "C" void kernel_launch(void* const* d_in, const int* in_sizes, int n_in,
                              void* d_out, int out_size, void* d_ws, size_t ws_size,
                              hipStream_t stream) {
  const float* x = (const float*)d_in[0];
  const float* wq = (const float*)d_in[1];
  const float* wk = (const float*)d_in[2];
  const float* wv = (const float*)d_in[3];
  float* out = (float*)d_out;

  char* ws = (char*)d_ws;
  __hip_bfloat16* wt = (__hip_bfloat16*)ws;                          // 3*512*512 bf16
  __hip_bfloat16* Qb = (__hip_bfloat16*)(ws + (size_t)3 * F_ * E_ * 2);
  __hip_bfloat16* Kb = Qb + (size_t)B_ * S_ * E_;
  __hip_bfloat16* Vt = Kb + (size_t)B_ * S_ * E_;
  // total ws use: 1.5MB + 3*16MB = 49.5MB

  dim3 b0(32, 8), g0(16, 16, 3);
  wtrans_kernel<<<g0, b0, 0, stream>>>(wq, wk, wv, wt);

  dim3 g1(128, 4, 3);
  qkv_kernel<<<g1, 256, 0, stream>>>(x, wt, Qb, Kb, Vt);

  attn_kernel<<<256, 256, 0, stream>>>(Qb, Kb, Vt, out);
}